// Round 2
// baseline (2170.114 us; speedup 1.0000x reference)
//
#include <hip/hip_runtime.h>
#include <math.h>

#define B_ 16
#define L_ 256
#define S_ 100
#define LA_ 48
#define NA_ 32
#define E_ 64
#define D_ 768
#define H_ 12
#define NHID_ 1024
#define WIDX_ 102
#define EPSF 1e-12f

// ---------------- meta: per-b sb, sls, last ----------------
__global__ void k_meta(const int* __restrict__ idxs, const int* __restrict__ blen,
                       int* __restrict__ meta) {
  int b = blockIdx.x, t = threadIdx.x;
  __shared__ int cnt;
  if (t == 0) cnt = 0;
  __syncthreads();
  if (t < WIDX_ && idxs[b * WIDX_ + t] > 0) atomicAdd(&cnt, 1);
  __syncthreads();
  if (t == 0) {
    int sb = cnt - 2;
    meta[b * 4 + 0] = sb;
    meta[b * 4 + 1] = idxs[b * WIDX_ + sb];  // sls
    meta[b * 4 + 2] = blen[b] - 1;           // last
  }
}

// ---------------- gather sent_emb (y<S) and arg_emb (y>=S) ----------------
__global__ void k_gather(const float* __restrict__ emb, const int* __restrict__ idxs,
                         const int* __restrict__ meta, float* __restrict__ sent_emb,
                         float* __restrict__ arg_emb) {
  int b = blockIdx.y, y = blockIdx.x, t = threadIdx.x;
  int sb = meta[b * 4 + 0], sls = meta[b * 4 + 1], last = meta[b * 4 + 2];
  if (y < S_) {
    int s = y;
    float* dst = sent_emb + ((size_t)b * S_ + s) * D_;
    if (s < sb) {
      const float* src = emb + ((size_t)b * L_ + idxs[b * WIDX_ + s]) * D_;
      for (int d = t; d < D_; d += 256) dst[d] = src[d];
    } else {
      for (int d = t; d < D_; d += 256) dst[d] = 0.f;
    }
  } else {
    int l = y - S_;
    int pos = sls + 1 + l;
    float* dst = arg_emb + ((size_t)b * LA_ + l) * D_;
    if (pos < last) {
      int p = pos > (L_ - 1) ? (L_ - 1) : pos;
      const float* src = emb + ((size_t)b * L_ + p) * D_;
      for (int d = t; d < D_; d += 256) dst[d] = src[d];
    } else {
      for (int d = t; d < D_; d += 256) dst[d] = 0.f;
    }
  }
}

// ---------------- trig: weighted mean over triggers ----------------
__global__ void k_trig(const float* __restrict__ sent_emb, const float* __restrict__ is_trig,
                       float* __restrict__ trig) {
  int b = blockIdx.y;
  int d = blockIdx.x * 256 + threadIdx.x;
  float acc = 0.f, den = 0.f;
  for (int s = 0; s < S_; s++) {
    float w = is_trig[b * S_ + s];
    den += w;
    if (w != 0.f) acc += w * sent_emb[((size_t)b * S_ + s) * D_ + d];
  }
  trig[b * D_ + d] = acc / den;
}

// ---------------- entity0 = ent_map^T @ sent_emb ; also e0*trig and nonempty ----------------
__global__ __launch_bounds__(256) void k_entity0(const float* __restrict__ sent_emb,
                                                 const float* __restrict__ ent_map,
                                                 const float* __restrict__ trig,
                                                 float* __restrict__ e0, float* __restrict__ e0t,
                                                 float* __restrict__ ne) {
  int b = blockIdx.y, e = blockIdx.x, t = threadIdx.x;
  float a0 = 0.f, a1 = 0.f, a2 = 0.f;
  for (int s = 0; s < S_; s++) {
    float w = ent_map[((size_t)b * S_ + s) * E_ + e];
    if (w != 0.f) {
      const float* r = sent_emb + ((size_t)b * S_ + s) * D_;
      a0 += w * r[t]; a1 += w * r[t + 256]; a2 += w * r[t + 512];
    }
  }
  size_t o = ((size_t)b * E_ + e) * D_;
  e0[o + t] = a0; e0[o + t + 256] = a1; e0[o + t + 512] = a2;
  const float* tr = trig + b * D_;
  e0t[o + t] = a0 * tr[t];
  e0t[o + t + 256] = a1 * tr[t + 256];
  e0t[o + t + 512] = a2 * tr[t + 512];
  __shared__ float red[256];
  red[t] = fabsf(a0) + fabsf(a1) + fabsf(a2);
  __syncthreads();
  for (int s2 = 128; s2 > 0; s2 >>= 1) {
    if (t < s2) red[t] += red[t + s2];
    __syncthreads();
  }
  if (t == 0) ne[b * E_ + e] = (red[0] > 0.f) ? 1.f : 0.f;
}

// ---------------- generic weighted sum: O[b,x,:] = sum_y W[b, y*sy + x*sx] * V[b,y,:] ----------------
__global__ __launch_bounds__(256) void k_wsum(const float* __restrict__ Wm, int wstride, int sy,
                                              int sx, const float* __restrict__ Vm,
                                              float* __restrict__ Om, int Y) {
  int b = blockIdx.y, x = blockIdx.x, t = threadIdx.x;
  float a0 = 0.f, a1 = 0.f, a2 = 0.f;
  const float* wb = Wm + (size_t)b * wstride + (size_t)x * sx;
  const float* vb = Vm + (size_t)b * Y * D_;
  for (int y = 0; y < Y; y++) {
    float w = wb[(size_t)y * sy];
    if (w != 0.f) {
      const float* r = vb + (size_t)y * D_;
      a0 += w * r[t]; a1 += w * r[t + 256]; a2 += w * r[t + 512];
    }
  }
  float* o = Om + ((size_t)b * gridDim.x + x) * D_;
  o[t] = a0; o[t + 256] = a1; o[t + 512] = a2;
}

// ---------------- tb[b,d] = b_ta[d] + sum_k trig[b,k]*W_ta[(D+k)*D + d] ----------------
__global__ void k_tb(const float* __restrict__ trig, const float* __restrict__ W_ta,
                     const float* __restrict__ b_ta, float* __restrict__ tb) {
  int b = blockIdx.y;
  int d = blockIdx.x * 256 + threadIdx.x;
  float acc = b_ta[d];
  for (int k = 0; k < D_; k++) acc += trig[b * D_ + k] * W_ta[(size_t)(D_ + k) * D_ + d];
  tb[b * D_ + d] = acc;
}

// ---------------- uber-GEMM: job table, 64x128 tile, split-K via atomicAdd ----------------
#define MAXJ 12
struct GJobs {
  const float* A[MAXJ];
  const float* Bw[MAXJ];
  float* C[MAXJ];
  int N[MAXJ], ntile[MAXJ], k0[MAXJ], niter[MAXJ];
  int tstart[MAXJ + 1];
  int njobs;
};

__global__ __launch_bounds__(256, 4) void k_gemmx(GJobs J) {
  __shared__ float As[2][16][68];
  __shared__ float BsL[2][16][68];
  __shared__ float BsH[2][16][68];
  int bx = blockIdx.x;
  int j = 0;
  while (j < J.njobs - 1 && bx >= J.tstart[j + 1]) j++;
  int local = bx - J.tstart[j];
  int nt = J.ntile[j];
  int by = local / nt;
  int bn0 = (local - by * nt) * 128;
  int N = J.N[j];
  int tid = threadIdx.x;
  int am = tid >> 2, ak = (tid & 3) << 2;
  int bk = tid >> 4, bn = (tid & 15) << 2;
  const float* Aj = J.A[j] + (size_t)(by * 64 + am) * D_ + J.k0[j] + ak;
  const float* Bj = J.Bw[j] + (size_t)(J.k0[j] + bk) * N + bn0 + bn;
  int niter = J.niter[j];
  float4 av = *(const float4*)Aj;
  float4 bL = *(const float4*)Bj;
  float4 bH = *(const float4*)(Bj + 64);
  As[0][ak + 0][am] = av.x; As[0][ak + 1][am] = av.y;
  As[0][ak + 2][am] = av.z; As[0][ak + 3][am] = av.w;
  *(float4*)&BsL[0][bk][bn] = bL;
  *(float4*)&BsH[0][bk][bn] = bH;
  float acc[4][8] = {};
  int tx = tid & 15, ty = tid >> 4;
  int buf = 0;
  for (int it = 0; it < niter; ++it) {
    __syncthreads();
    bool more = (it + 1 < niter);
    if (more) {
      av = *(const float4*)(Aj + (it + 1) * 16);
      bL = *(const float4*)(Bj + (size_t)(it + 1) * 16 * N);
      bH = *(const float4*)(Bj + (size_t)(it + 1) * 16 * N + 64);
    }
#define FMAROW(i, as)                                                      \
  acc[i][0] += (as)*bl.x; acc[i][1] += (as)*bl.y; acc[i][2] += (as)*bl.z;  \
  acc[i][3] += (as)*bl.w; acc[i][4] += (as)*bh.x; acc[i][5] += (as)*bh.y;  \
  acc[i][6] += (as)*bh.z; acc[i][7] += (as)*bh.w;
#pragma unroll
    for (int k = 0; k < 16; ++k) {
      float4 a4 = *(const float4*)&As[buf][k][ty * 4];
      float4 bl = *(const float4*)&BsL[buf][k][tx * 4];
      float4 bh = *(const float4*)&BsH[buf][k][tx * 4];
      FMAROW(0, a4.x) FMAROW(1, a4.y) FMAROW(2, a4.z) FMAROW(3, a4.w)
    }
    if (more) {
      buf ^= 1;
      As[buf][ak + 0][am] = av.x; As[buf][ak + 1][am] = av.y;
      As[buf][ak + 2][am] = av.z; As[buf][ak + 3][am] = av.w;
      *(float4*)&BsL[buf][bk][bn] = bL;
      *(float4*)&BsH[buf][bk][bn] = bH;
    }
  }
  float* Cj = J.C[j];
#pragma unroll
  for (int i = 0; i < 4; ++i) {
    int row = by * 64 + ty * 4 + i;
    float* cr = Cj + (size_t)row * N + bn0;
#pragma unroll
    for (int q = 0; q < 4; ++q) {
      atomicAdd(cr + tx * 4 + q, acc[i][q]);
      atomicAdd(cr + 64 + tx * 4 + q, acc[i][q + 4]);
    }
  }
}

// ---------------- entity_new epilogue: (C + tb[b]) * nonempty ----------------
__global__ void k_entnew_ep(float* __restrict__ C, const float* __restrict__ tb,
                            const float* __restrict__ ne) {
  int r = blockIdx.x, t = threadIdx.x;
  int b = r >> 6;
  float m = ne[r];
  size_t o = (size_t)r * D_;
  for (int d = t; d < D_; d += 256) C[o + d] = (C[o + d] + tb[b * D_ + d]) * m;
}

// ---------------- score[b,e,a] = dot(entity_new[b,e], arg[b,a]) / sqrt(D) ----------------
__global__ __launch_bounds__(256) void k_score(const float* __restrict__ entn,
                                               const float* __restrict__ argm,
                                               float* __restrict__ score) {
  int b = blockIdx.y, e = blockIdx.x, t = threadIdx.x;
  __shared__ float ent[D_];
  const float* er = entn + ((size_t)b * E_ + e) * D_;
  for (int d = t; d < D_; d += 256) ent[d] = er[d];
  __syncthreads();
  int wave = t >> 6, lane = t & 63;
  const float scale = 0.03608439182435161f;  // 1/sqrt(768)
  for (int a = wave; a < NA_; a += 4) {
    const float* ar = argm + ((size_t)b * NA_ + a) * D_;
    float p = 0.f;
#pragma unroll
    for (int i = 0; i < 12; i++) {
      int d = lane + 64 * i;
      p += ent[d] * ar[d];
    }
    for (int off = 32; off > 0; off >>= 1) p += __shfl_down(p, off);
    if (lane == 0) score[((size_t)b * E_ + e) * NA_ + a] = p * scale;
  }
}

// ---------------- L1 normalize over a (t2a) and over e (a2t) ----------------
__global__ void k_norm(const float* __restrict__ score, float* __restrict__ t2a,
                       float* __restrict__ a2t) {
  int b = blockIdx.x, t = threadIdx.x;
  __shared__ float s[E_ * NA_];
  __shared__ float rs[E_];
  __shared__ float cs[NA_];
  for (int i = t; i < E_ * NA_; i += 256) s[i] = score[(size_t)b * E_ * NA_ + i];
  __syncthreads();
  if (t < E_) {
    float sum = 0.f;
    for (int a = 0; a < NA_; a++) sum += fabsf(s[t * NA_ + a]);
    rs[t] = fmaxf(sum, EPSF);
  } else if (t >= 64 && t < 96) {
    int a = t - 64;
    float sum = 0.f;
    for (int e = 0; e < E_; e++) sum += fabsf(s[e * NA_ + a]);
    cs[a] = fmaxf(sum, EPSF);
  }
  __syncthreads();
  for (int i = t; i < E_ * NA_; i += 256) {
    int e = i >> 5, a = i & 31;
    float v = s[i];
    t2a[(size_t)b * E_ * NA_ + i] = v / rs[e];
    a2t[(size_t)b * E_ * NA_ + i] = v / cs[a];
  }
}

// ---------------- a2a = softmax(arg @ arg^T) ----------------
__global__ __launch_bounds__(256) void k_a2a(const float* __restrict__ argm,
                                             float* __restrict__ a2a) {
  int b = blockIdx.y, a = blockIdx.x, t = threadIdx.x;
  __shared__ float sA[D_];
  __shared__ float lg[NA_];
  const float* ar = argm + ((size_t)b * NA_ + a) * D_;
  for (int d = t; d < D_; d += 256) sA[d] = ar[d];
  __syncthreads();
  int wave = t >> 6, lane = t & 63;
  for (int a2 = wave; a2 < NA_; a2 += 4) {
    const float* br = argm + ((size_t)b * NA_ + a2) * D_;
    float p = 0.f;
#pragma unroll
    for (int i = 0; i < 12; i++) {
      int d = lane + 64 * i;
      p += sA[d] * br[d];
    }
    for (int off = 32; off > 0; off >>= 1) p += __shfl_down(p, off);
    if (lane == 0) lg[a2] = p;
  }
  __syncthreads();
  if (t < 64) {
    float v = (t < NA_) ? lg[t] : -INFINITY;
    float m = v;
    for (int mask = 16; mask > 0; mask >>= 1) m = fmaxf(m, __shfl_xor(m, mask));
    float ex = (t < NA_) ? expf(v - m) : 0.f;
    float sm = ex;
    for (int mask = 16; mask > 0; mask >>= 1) sm += __shfl_xor(sm, mask);
    if (t < NA_) a2a[((size_t)b * NA_ + a) * NA_ + t] = ex / sm;
  }
}

// ---------------- t2t: gathered, head-mean, per-att row-normalized, averaged ----------------
__global__ __launch_bounds__(128) void k_t2t(const float* __restrict__ att0,
                                             const float* __restrict__ att1,
                                             const float* __restrict__ att2,
                                             const int* __restrict__ idxs,
                                             const int* __restrict__ meta,
                                             float* __restrict__ t2t) {
  int b = blockIdx.y, s = blockIdx.x, t = threadIdx.x;
  int sb = meta[b * 4 + 0];
  float* out = t2t + ((size_t)b * S_ + s) * S_;
  if (s >= sb) {
    for (int j = t; j < S_; j += 128) out[j] = 0.f;
    return;
  }
  int Is = idxs[b * WIDX_ + s];
  int It = (t < S_) ? idxs[b * WIDX_ + t] : 0;
  __shared__ float row[256];
  __shared__ float red[128];
  const float* atts[3] = {att0, att1, att2};
  float accout = 0.f;
  for (int q = 0; q < 3; q++) {
    float r0 = 0.f, r1 = 0.f;
    const float* base = atts[q] + (((size_t)b * H_) * L_ + Is) * L_;
    for (int h = 0; h < H_; h++) {
      const float* rp = base + (size_t)h * L_ * L_;
      r0 += rp[t];
      r1 += rp[t + 128];
    }
    row[t] = r0;
    row[t + 128] = r1;
    __syncthreads();
    float v = (t < sb) ? row[It] * (1.f / 12.f) : 0.f;
    red[t] = v;
    __syncthreads();
    for (int s2 = 64; s2 > 0; s2 >>= 1) {
      if (t < s2) red[t] += red[t + s2];
      __syncthreads();
    }
    float rsum = red[0];
    __syncthreads();
    accout += v / fmaxf(rsum, EPSF) * (1.f / 3.f);
  }
  if (t < S_) out[t] = accout;
}

// ---------------- final: out = gelu(Pe + Pa + b1) @ W2 + b2 ----------------
__global__ __launch_bounds__(256) void k_final(const float* __restrict__ Pe,
                                               const float* __restrict__ Pa,
                                               const float* __restrict__ b1,
                                               const float* __restrict__ W2,
                                               const float* __restrict__ b2,
                                               float* __restrict__ out) {
  int b = blockIdx.y, e = blockIdx.x, t = threadIdx.x;
  __shared__ float pe[NHID_];
  const float* per = Pe + ((size_t)b * E_ + e) * NHID_;
  for (int n = t; n < NHID_; n += 256) pe[n] = per[n] + b1[n];
  __syncthreads();
  int a = t >> 3, c = t & 7;
  const float* par = Pa + ((size_t)b * NA_ + a) * NHID_;
  float acc = 0.f;
#pragma unroll 4
  for (int jj = 0; jj < 128; ++jj) {
    int n = c * 128 + jj;
    float x = pe[n] + par[n];
    float g = 0.5f * x * (1.f + erff(x * 0.70710678118654752f));
    acc += g * W2[n];
  }
  acc += __shfl_down(acc, 4);
  acc += __shfl_down(acc, 2);
  acc += __shfl_down(acc, 1);
  if (c == 0) out[((size_t)b * E_ + e) * NA_ + a] = acc + b2[0];
}

extern "C" void kernel_launch(void* const* d_in, const int* in_sizes, int n_in,
                              void* d_out, int out_size, void* d_ws, size_t ws_size,
                              hipStream_t stream) {
  const float* emb    = (const float*)d_in[0];
  const float* istrig = (const float*)d_in[1];
  const float* argw   = (const float*)d_in[2];
  const float* entmap = (const float*)d_in[3];
  const float* att0   = (const float*)d_in[4];
  const float* att1   = (const float*)d_in[5];
  const float* att2   = (const float*)d_in[6];
  const float* W_ta   = (const float*)d_in[7];
  const float* b_ta   = (const float*)d_in[8];
  const float* W1     = (const float*)d_in[9];
  const float* b1     = (const float*)d_in[10];
  const float* W2     = (const float*)d_in[11];
  const float* b2     = (const float*)d_in[12];
  const int*   idxs   = (const int*)d_in[13];
  const int*   blen   = (const int*)d_in[14];
  float* out = (float*)d_out;

  float* ws = (float*)d_ws;
  size_t o = 0;
  int* meta = (int*)ws; o += 256;
  float* sent_emb = ws + o; o += (size_t)B_ * S_ * D_;
  float* arg_emb  = ws + o; o += (size_t)B_ * LA_ * D_;
  float* trig     = ws + o; o += (size_t)B_ * D_;
  float* e0       = ws + o; o += (size_t)B_ * E_ * D_;
  float* e0t      = ws + o; o += (size_t)B_ * E_ * D_;
  float* argm     = ws + o; o += (size_t)B_ * NA_ * D_;
  float* entn     = ws + o; o += (size_t)B_ * E_ * D_;
  float* tb       = ws + o; o += (size_t)B_ * D_;
  float* ne       = ws + o; o += (size_t)B_ * E_;
  float* score    = ws + o; o += (size_t)B_ * E_ * NA_;
  float* t2a      = ws + o; o += (size_t)B_ * E_ * NA_;
  float* a2t      = ws + o; o += (size_t)B_ * E_ * NA_;
  float* t2t      = ws + o; o += (size_t)B_ * S_ * S_;
  float* ah2h     = ws + o; o += (size_t)B_ * S_ * D_;
  float* Ah2h     = ws + o; o += (size_t)B_ * E_ * D_;
  float* tokA     = ws + o; o += (size_t)B_ * E_ * D_;
  float* argTok   = ws + o; o += (size_t)B_ * NA_ * D_;
  float* a2a      = ws + o; o += (size_t)B_ * NA_ * NA_;
  float* Au2u     = ws + o; o += (size_t)B_ * NA_ * D_;
  float* Pe       = ws + o; o += (size_t)B_ * E_ * NHID_;
  float* Pa       = ws + o; o += (size_t)B_ * NA_ * NHID_;

  // zero the split-K accumulation targets (Pe,Pa contiguous)
  hipMemsetAsync(entn, 0, (size_t)B_ * E_ * D_ * sizeof(float), stream);
  hipMemsetAsync(Pe, 0, ((size_t)B_ * E_ * NHID_ + (size_t)B_ * NA_ * NHID_) * sizeof(float),
                 stream);

  // ---- phase A: gathers + everything not depending on entity_new ----
  k_meta<<<B_, 128, 0, stream>>>(idxs, blen, meta);
  k_gather<<<dim3(S_ + LA_, B_), 256, 0, stream>>>(emb, idxs, meta, sent_emb, arg_emb);
  k_trig<<<dim3(3, B_), 256, 0, stream>>>(sent_emb, istrig, trig);
  k_entity0<<<dim3(E_, B_), 256, 0, stream>>>(sent_emb, entmap, trig, e0, e0t, ne);
  k_wsum<<<dim3(NA_, B_), 256, 0, stream>>>(argw, LA_ * NA_, NA_, 1, arg_emb, argm, LA_);
  k_tb<<<dim3(3, B_), 256, 0, stream>>>(trig, W_ta, b_ta, tb);
  k_t2t<<<dim3(S_, B_), 128, 0, stream>>>(att0, att1, att2, idxs, meta, t2t);
  k_wsum<<<dim3(S_, B_), 256, 0, stream>>>(t2t, S_ * S_, 1, S_, sent_emb, ah2h, S_);
  k_wsum<<<dim3(E_, B_), 256, 0, stream>>>(entmap, S_ * E_, E_, 1, ah2h, Ah2h, S_);
  k_a2a<<<dim3(NA_, B_), 256, 0, stream>>>(argm, a2a);
  k_wsum<<<dim3(NA_, B_), 256, 0, stream>>>(a2a, NA_ * NA_, 1, NA_, argm, Au2u, NA_);

  // ---- phase B: uber-GEMM (entn p0/p1, Pe<-e0,Ah2h, Pa<-argm,Au2u), split-K x2 ----
  GJobs JB = {};
  {
    int jn = 0, tt = 0;
    auto add = [&](const float* A, const float* Bw, float* C, int N, int mt, int k0, int klen) {
      JB.A[jn] = A; JB.Bw[jn] = Bw; JB.C[jn] = C; JB.N[jn] = N;
      JB.ntile[jn] = N / 128; JB.k0[jn] = k0; JB.niter[jn] = klen / 16;
      JB.tstart[jn] = tt; tt += mt * (N / 128); jn++;
    };
    add(e0, W_ta, entn, D_, 16, 0, 384);
    add(e0, W_ta, entn, D_, 16, 384, 384);
    add(e0t, W_ta + (size_t)2 * D_ * D_, entn, D_, 16, 0, 384);
    add(e0t, W_ta + (size_t)2 * D_ * D_, entn, D_, 16, 384, 384);
    add(e0, W1, Pe, NHID_, 16, 0, 384);
    add(e0, W1, Pe, NHID_, 16, 384, 384);
    add(Ah2h, W1 + (size_t)3 * D_ * NHID_, Pe, NHID_, 16, 0, 384);
    add(Ah2h, W1 + (size_t)3 * D_ * NHID_, Pe, NHID_, 16, 384, 384);
    add(argm, W1 + (size_t)D_ * NHID_, Pa, NHID_, 8, 0, 384);
    add(argm, W1 + (size_t)D_ * NHID_, Pa, NHID_, 8, 384, 384);
    add(Au2u, W1 + (size_t)5 * D_ * NHID_, Pa, NHID_, 8, 0, 384);
    add(Au2u, W1 + (size_t)5 * D_ * NHID_, Pa, NHID_, 8, 384, 384);
    JB.njobs = jn; JB.tstart[jn] = tt;
    k_gemmx<<<tt, 256, 0, stream>>>(JB);
  }

  // ---- phase C: entity_new epilogue + score path ----
  k_entnew_ep<<<B_ * E_, 256, 0, stream>>>(entn, tb, ne);
  k_score<<<dim3(E_, B_), 256, 0, stream>>>(entn, argm, score);
  k_norm<<<B_, 256, 0, stream>>>(score, t2a, a2t);
  k_wsum<<<dim3(E_, B_), 256, 0, stream>>>(t2a, E_ * NA_, 1, NA_, argm, tokA, NA_);
  k_wsum<<<dim3(NA_, B_), 256, 0, stream>>>(a2t, E_ * NA_, NA_, 1, entn, argTok, E_);

  // ---- phase D: remaining GEMM (Pe<-tokA, Pa<-argTok), split-K x3 ----
  GJobs JD = {};
  {
    int jn = 0, tt = 0;
    auto add = [&](const float* A, const float* Bw, float* C, int N, int mt, int k0, int klen) {
      JD.A[jn] = A; JD.Bw[jn] = Bw; JD.C[jn] = C; JD.N[jn] = N;
      JD.ntile[jn] = N / 128; JD.k0[jn] = k0; JD.niter[jn] = klen / 16;
      JD.tstart[jn] = tt; tt += mt * (N / 128); jn++;
    };
    add(tokA, W1 + (size_t)2 * D_ * NHID_, Pe, NHID_, 16, 0, 256);
    add(tokA, W1 + (size_t)2 * D_ * NHID_, Pe, NHID_, 16, 256, 256);
    add(tokA, W1 + (size_t)2 * D_ * NHID_, Pe, NHID_, 16, 512, 256);
    add(argTok, W1 + (size_t)4 * D_ * NHID_, Pa, NHID_, 8, 0, 256);
    add(argTok, W1 + (size_t)4 * D_ * NHID_, Pa, NHID_, 8, 256, 256);
    add(argTok, W1 + (size_t)4 * D_ * NHID_, Pa, NHID_, 8, 512, 256);
    JD.njobs = jn; JD.tstart[jn] = tt;
    k_gemmx<<<tt, 256, 0, stream>>>(JD);
  }

  // ---- final ----
  k_final<<<dim3(E_, B_), 256, 0, stream>>>(Pe, Pa, b1, W2, b2, out);
}